// Round 15
// baseline (97.735 us; speedup 1.0000x reference)
//
#include <hip/hip_runtime.h>
#include <stdint.h>
#include <math.h>

#define TPB 256
#define CH 16           // chunk-blocks per row for heavy passes
#define LISTCAP 192     // per-row final-bin list (lambda~68 at 17-bit prefix)
#define FB_TPB 1024
#define FB_TIE 1024
#define S_FIX 4096.0f   // fixed-point scale: mass units of 2^-12
// Finite "dropped" sentinel — must be finite IN BF16 TOO (harness diffs via a
// bf16 cast; -FLT_MAX/-inf become bf16 -inf -> (-inf)-(-inf)=NaN -> fail).
#define DROPV (-1.0e30f)

// order-preserving float->uint32 key (ascending)
__device__ __forceinline__ uint32_t tokey(float f) {
  uint32_t b = __float_as_uint(f);
  return (b & 0x80000000u) ? ~b : (b | 0x80000000u);
}
__device__ __forceinline__ float fromkey(uint32_t k) {
  uint32_t b = (k & 0x80000000u) ? (k ^ 0x80000000u) : ~k;
  return __uint_as_float(b);
}
__device__ __forceinline__ float scrub(float f) {
  uint32_t b = __float_as_uint(f) & 0x7FFFFFFFu;
  if (b >= 0x7F7F0000u) return DROPV;  // inf/NaN or bf16-inf-rounding -> DROPV
  return f;
}
__device__ __forceinline__ unsigned long long tofix(float u) {
  return (unsigned long long)(u * S_FIX);
}

// wave 0: pick lowest bin where running mass crosses THR (bins exact ints in double)
__device__ __forceinline__ void wave_selectD(const double* __restrict__ bins, int nb,
                                             int bits, int lane,
                                             double* sP, uint32_t* sPrefix, double THR) {
  const int per = nb >> 6;
  double lsum = 0.0;
  for (int k = 0; k < per; ++k) lsum += bins[lane * per + k];
  double v = lsum;
#pragma unroll
  for (int off = 1; off < 64; off <<= 1) {
    double o = __shfl_up(v, off, 64);
    if (lane >= off) v += o;
  }
  const double excl = v - lsum;
  const double P = *sP;
  int lbin = -1;
  double lP = 0.0;
  double rr = P + excl;
  for (int k = 0; k < per; ++k) {
    double m = bins[lane * per + k];
    double nr = rr + m;
    if (lbin < 0 && nr > THR) { lbin = lane * per + k; lP = rr; }
    rr = nr;
  }
  unsigned long long got = __ballot(lbin >= 0);
  int bsel;
  double Pn;
  if (got) {
    int src = __ffsll(got) - 1;  // lowest crossing bin
    bsel = __shfl(lbin, src, 64);
    Pn = __shfl(lP, src, 64);
  } else {
    int hb = -1;
    double pb = P;
    rr = P + excl;
    for (int k = 0; k < per; ++k) {
      double m = bins[lane * per + k];
      if (m > 0.0) { hb = lane * per + k; pb = rr; }
      rr += m;
    }
#pragma unroll
    for (int off = 32; off; off >>= 1) {
      int ob = __shfl_xor(hb, off, 64);
      double opb = __shfl_xor(pb, off, 64);
      if (ob > hb) { hb = ob; pb = opb; }
    }
    bsel = hb < 0 ? (nb - 1) : hb;
    Pn = pb;
  }
  if (lane == 0) {
    *sPrefix = (*sPrefix << bits) | (uint32_t)bsel;
    *sP = Pn;
  }
}

// Block-head select level 0 (9 bits from gh0). Deterministic: every block
// derives the identical result from the identical finalized histogram.
// db must be double[512] LDS; outputs via sP/sThr/sPfx LDS scalars.
__device__ __forceinline__ void head_select0(const unsigned long long* __restrict__ gh0,
                                             double* db, int tid, int lane,
                                             double* sP, double* sThr, uint32_t* sPfx) {
  if (tid < 64) {
    double t = 0.0;
    for (int i = lane; i < 512; i += 64) {
      double d = (double)gh0[i];  // exact int < 2^53
      db[i] = d;
      t += d;
    }
#pragma unroll
    for (int off = 32; off; off >>= 1) t += __shfl_xor(t, off, 64);
    if (lane == 0) { *sThr = (double)0.1f * t; *sP = 0.0; *sPfx = 0u; }  // 0.1f as ref
  }
  __syncthreads();
  if (tid < 64) wave_selectD(db, 512, 9, lane, sP, sPfx, *sThr);
  __syncthreads();
}

// Block-head select level 1 (8 more bits from gh1) -> 17-bit prefix.
__device__ __forceinline__ void head_select1(const unsigned long long* __restrict__ gh1,
                                             double* db, int tid, int lane,
                                             double* sP, double* sThr, uint32_t* sPfx) {
  if (tid < 64) {
    for (int i = lane; i < 256; i += 64) db[i] = (double)gh1[i];
  }
  __syncthreads();
  if (tid < 64) wave_selectD(db, 256, 8, lane, sP, sPfx, *sThr);
  __syncthreads();
}

__global__ void zeroK(uint32_t* p, int n) {
  int i = blockIdx.x * blockDim.x + threadIdx.x;
  if (i < n) p[i] = 0u;
}

// K1: L0 9-bit (bits[31:23]) mass histogram, u64 fixed-point, 4-replica LDS.
__global__ __launch_bounds__(TPB) void histZK(const float* __restrict__ x, int V,
                                              unsigned long long* __restrict__ ghist0) {
  const int row = blockIdx.y, chunk = blockIdx.x, tid = threadIdx.x;
  const float* rowp = x + (size_t)row * (size_t)V;
  __shared__ unsigned long long h[2048];  // 512 bins x 4 replicas = 16 KB
  for (int i = tid; i < 2048; i += TPB) h[i] = 0ull;
  __syncthreads();

  const int epc = (((V + CH - 1) / CH) + 3) & ~3;
  const int start = chunk * epc, end = min(start + epc, V);
  const int vs = start >> 2, ve = end >> 2;
  const int rep = tid & 3;
  auto acc = [&](float4 v) {
    float vv[4] = {v.x, v.y, v.z, v.w};
#pragma unroll
    for (int k = 0; k < 4; ++k)
      atomicAdd(&h[(((tokey(vv[k]) >> 23) << 2) | rep)], tofix(__expf(vv[k])));
  };
  for (int i = vs + tid; i < ve; i += 2 * TPB) {  // batch-2 float4 (round-10 proven)
    const int i1 = i + TPB;
    const bool g1 = i1 < ve;
    float4 a = *reinterpret_cast<const float4*>(rowp + 4 * i);
    float4 b;
    if (g1) b = *reinterpret_cast<const float4*>(rowp + 4 * i1);
    acc(a);
    if (g1) acc(b);
  }
  for (int i = (ve << 2) + tid; i < end; i += TPB)  // scalar tail
    atomicAdd(&h[(((tokey(rowp[i]) >> 23) << 2) | rep)], tofix(__expf(rowp[i])));
  __syncthreads();
  unsigned long long* gh = ghist0 + (size_t)row * 512;
  for (int b = tid; b < 512; b += TPB) {
    unsigned long long s = h[4 * b] + h[4 * b + 1] + h[4 * b + 2] + h[4 * b + 3];
    if (s) atomicAdd(&gh[b], s);
  }
}

// K2: head re-derives L0 select; classify + write output + 8-bit L1 subhist
// (bits[22:15]) of the boundary bin into separate gh1 region.
__global__ __launch_bounds__(TPB) void outSelK(const float* __restrict__ x,
                                               float* __restrict__ out, int V,
                                               const unsigned long long* __restrict__ ghist0,
                                               unsigned long long* __restrict__ ghist1) {
  const int row = blockIdx.y, chunk = blockIdx.x, tid = threadIdx.x, lane = tid & 63;
  const float* rowp = x + (size_t)row * (size_t)V;
  float* orow = out + (size_t)row * (size_t)V;
  __shared__ double db[512];
  __shared__ unsigned long long h[256];
  __shared__ double sP, sThr;
  __shared__ uint32_t sPfx;

  head_select0(ghist0 + (size_t)row * 512, db, tid, lane, &sP, &sThr, &sPfx);
  const uint32_t pfx9 = sPfx;
  for (int i = tid; i < 256; i += TPB) h[i] = 0ull;
  __syncthreads();

  const int epc = (((V + CH - 1) / CH) + 3) & ~3;
  const int start = chunk * epc, end = min(start + epc, V);
  const int vs = start >> 2, ve = end >> 2;
  auto proc = [&](float4 v, int i) {
    float vv[4] = {v.x, v.y, v.z, v.w};
    float ov[4];
#pragma unroll
    for (int k = 0; k < 4; ++k) {
      uint32_t key = tokey(vv[k]);
      uint32_t top = key >> 23;
      ov[k] = (top > pfx9) ? scrub(vv[k]) : DROPV;  // boundary: placeholder
      if (top == pfx9) atomicAdd(&h[(key >> 15) & 255u], tofix(__expf(vv[k])));
    }
    *reinterpret_cast<float4*>(orow + 4 * i) = make_float4(ov[0], ov[1], ov[2], ov[3]);
  };
  for (int i = vs + tid; i < ve; i += 2 * TPB) {
    const int i1 = i + TPB;
    const bool g1 = i1 < ve;
    float4 a = *reinterpret_cast<const float4*>(rowp + 4 * i);
    float4 b;
    if (g1) b = *reinterpret_cast<const float4*>(rowp + 4 * i1);
    proc(a, i);
    if (g1) proc(b, i1);
  }
  for (int i = (ve << 2) + tid; i < end; i += TPB) {
    float f = rowp[i];
    uint32_t key = tokey(f), top = key >> 23;
    orow[i] = (top > pfx9) ? scrub(f) : DROPV;
    if (top == pfx9) atomicAdd(&h[(key >> 15) & 255u], tofix(__expf(f)));
  }
  __syncthreads();
  unsigned long long* gh1 = ghist1 + (size_t)row * 256;
  for (int b = tid; b < 256; b += TPB)
    if (h[b]) atomicAdd(&gh1[b], h[b]);
}

// K3: head re-derives L0+L1 selects -> 17-bit prefix; restore kept boundary
// elements above the L1 bin; collect L1-bin elements.
__global__ __launch_bounds__(TPB) void colSelK(const float* __restrict__ x,
                                               float* __restrict__ out, int V,
                                               const unsigned long long* __restrict__ ghist0,
                                               const unsigned long long* __restrict__ ghist1,
                                               uint2* __restrict__ glist,
                                               uint32_t* __restrict__ gcnt) {
  const int row = blockIdx.y, chunk = blockIdx.x, tid = threadIdx.x, lane = tid & 63;
  const float* rowp = x + (size_t)row * (size_t)V;
  float* orow = out + (size_t)row * (size_t)V;
  __shared__ double db[512];
  __shared__ double sP, sThr;
  __shared__ uint32_t sPfx;

  head_select0(ghist0 + (size_t)row * 512, db, tid, lane, &sP, &sThr, &sPfx);
  head_select1(ghist1 + (size_t)row * 256, db, tid, lane, &sP, &sThr, &sPfx);
  const uint32_t pfx17 = sPfx;
  const uint32_t pfx9 = pfx17 >> 8;
  const uint32_t l1bin = pfx17 & 255u;

  const int epc = (((V + CH - 1) / CH) + 3) & ~3;
  const int start = chunk * epc, end = min(start + epc, V);
  const int vs = start >> 2, ve = end >> 2;
  auto proc = [&](float f, int idx) {
    uint32_t key = tokey(f);
    if ((key >> 23) == pfx9) {
      uint32_t mid = (key >> 15) & 255u;
      if (mid > l1bin) {
        orow[idx] = scrub(f);  // definitely kept
      } else if (mid == l1bin) {
        uint32_t p = atomicAdd(gcnt + row, 1u);
        if (p < LISTCAP) glist[(size_t)row * LISTCAP + p] = make_uint2(key, (uint32_t)idx);
      }  // mid < l1bin: DROPV placeholder already correct
    }
  };
  auto proc4 = [&](float4 v, int i) {
    proc(v.x, 4 * i); proc(v.y, 4 * i + 1); proc(v.z, 4 * i + 2); proc(v.w, 4 * i + 3);
  };
  for (int i = vs + tid; i < ve; i += 2 * TPB) {
    const int i1 = i + TPB;
    const bool g1 = i1 < ve;
    float4 a = *reinterpret_cast<const float4*>(rowp + 4 * i);
    float4 b;
    if (g1) b = *reinterpret_cast<const float4*>(rowp + 4 * i1);
    proc4(a, i);
    if (g1) proc4(b, i1);
  }
  for (int i = (ve << 2) + tid; i < end; i += TPB) proc(rowp[i], i);
}

// K4: one block per row; head re-derives selects; exact finalize of the
// L1-bin candidates: parallel rank-sort + cumulative walk in stable order.
__global__ __launch_bounds__(TPB) void finSelK(const float* __restrict__ x,
                                               float* __restrict__ out, int V,
                                               const unsigned long long* __restrict__ ghist0,
                                               const unsigned long long* __restrict__ ghist1,
                                               const uint2* __restrict__ glist,
                                               const uint32_t* __restrict__ gcnt) {
  const int row = blockIdx.x, tid = threadIdx.x, lane = tid & 63;
  const float* rowp = x + (size_t)row * (size_t)V;
  float* orow = out + (size_t)row * (size_t)V;
  __shared__ double db[512];
  __shared__ double sP, sThr;
  __shared__ uint32_t sPfx;
  __shared__ uint2 ls[2048];
  __shared__ uint2 srt[2048];
  __shared__ unsigned char keep[2048];
  __shared__ uint32_t scnt;

  head_select0(ghist0 + (size_t)row * 512, db, tid, lane, &sP, &sThr, &sPfx);
  head_select1(ghist1 + (size_t)row * 256, db, tid, lane, &sP, &sThr, &sPfx);
  const uint32_t pfx17 = sPfx;
  const double P = sP, THR = sThr;

  const uint32_t n0 = gcnt[row];
  if (tid == 0) scnt = 0u;
  __syncthreads();
  uint32_t m;
  if (n0 <= LISTCAP) {
    for (uint32_t i = tid; i < n0; i += TPB) ls[i] = glist[(size_t)row * LISTCAP + i];
    m = n0;
    __syncthreads();
  } else {
    // overflow fallback (statistically never): parallel vectorized rescan
    const int nvec = V >> 2;
    for (int i = tid; i < nvec; i += TPB) {
      float4 v = *reinterpret_cast<const float4*>(rowp + 4 * i);
      float vv[4] = {v.x, v.y, v.z, v.w};
#pragma unroll
      for (int k = 0; k < 4; ++k) {
        uint32_t key = tokey(vv[k]);
        if ((key >> 15) == pfx17) {
          uint32_t p = atomicAdd(&scnt, 1u);
          if (p < 2048u) ls[p] = make_uint2(key, (uint32_t)(4 * i + k));
        }
      }
    }
    for (int i = (nvec << 2) + tid; i < V; i += TPB) {
      uint32_t key = tokey(rowp[i]);
      if ((key >> 15) == pfx17) {
        uint32_t p = atomicAdd(&scnt, 1u);
        if (p < 2048u) ls[p] = make_uint2(key, (uint32_t)i);
      }
    }
    __syncthreads();
    m = min(scnt, 2048u);
  }

  // parallel rank placement: rank by (key, idx) — unique since idx unique
  for (uint32_t j = tid; j < m; j += TPB) {
    uint2 kv = ls[j];
    uint32_t r = 0;
    for (uint32_t i = 0; i < m; ++i) {
      uint2 o = ls[i];
      if (o.x < kv.x || (o.x == kv.x && o.y < kv.y)) ++r;
    }
    srt[r] = kv;
  }
  __syncthreads();
  if (tid == 0) {
    // cumulative walk in ascending stable order == ref's sorted cumsum
    double cum = P;  // fix-units
    for (uint32_t j = 0; j < m; ++j) {
      cum += (double)__expf(fromkey(srt[j].x)) * (double)S_FIX;
      keep[j] = (cum > THR) ? 1 : 0;
    }
  }
  __syncthreads();
  for (uint32_t j = tid; j < m; j += TPB)
    orow[srt[j].y] = keep[j] ? scrub(fromkey(srt[j].x)) : DROPV;
}

// ---------------- fallback: proven single-kernel path (ws too small) ----------------
__global__ __launch_bounds__(FB_TPB) void toppK_fb(const float* __restrict__ x,
                                                   float* __restrict__ out, int V) {
  const int row = blockIdx.x;
  const int tid = threadIdx.x;
  const int lane = tid & 63;
  const float* rowp = x + (size_t)row * (size_t)V;
  float* orow = out + (size_t)row * (size_t)V;
  const int nvec = V >> 2;
  const int tail = nvec << 2;

  __shared__ float smass[2048];
  __shared__ double zw[FB_TPB / 64];
  __shared__ double sTHR, sP;
  __shared__ uint32_t sPrefix;
  __shared__ uint32_t sTie[FB_TIE];
  __shared__ uint32_t sTieCnt;
  __shared__ int sD;

  if (tid == 0) { sTieCnt = 0u; sPrefix = 0u; sP = 0.0; sTHR = 0.0; sD = 0; }
  const int shifts[3] = {21, 10, 0};
  const int bitsA[3] = {11, 11, 10};

  for (int L = 0; L < 3; ++L) {
    const int nb = 1 << bitsA[L];
    for (int i = tid; i < nb; i += FB_TPB) smass[i] = 0.f;
    __syncthreads();
    const uint32_t pfx = sPrefix;
    float zloc = 0.f;
    for (int i = tid; i < nvec; i += FB_TPB) {
      float4 v = *reinterpret_cast<const float4*>(rowp + 4 * i);
      float vv[4] = {v.x, v.y, v.z, v.w};
#pragma unroll
      for (int k = 0; k < 4; ++k) {
        uint32_t key = tokey(vv[k]);
        if (L == 0) {
          float u = __expf(vv[k]);
          zloc += u;
          atomicAdd(&smass[key >> 21], u);
        } else if ((key >> (shifts[L] + bitsA[L])) == pfx) {
          atomicAdd(&smass[(key >> shifts[L]) & (uint32_t)(nb - 1)], __expf(vv[k]));
        }
      }
    }
    for (int i = tail + tid; i < V; i += FB_TPB) {
      float f = rowp[i];
      uint32_t key = tokey(f);
      if (L == 0) {
        float u = __expf(f);
        zloc += u;
        atomicAdd(&smass[key >> 21], u);
      } else if ((key >> (shifts[L] + bitsA[L])) == pfx) {
        atomicAdd(&smass[(key >> shifts[L]) & (uint32_t)(nb - 1)], __expf(f));
      }
    }
    if (L == 0) {
      double z = (double)zloc;
#pragma unroll
      for (int off = 32; off; off >>= 1) z += __shfl_down(z, off, 64);
      if (lane == 0) zw[tid >> 6] = z;
    }
    __syncthreads();
    if (L == 0 && tid == 0) {
      double Z = 0.0;
      for (int w = 0; w < FB_TPB / 64; ++w) Z += zw[w];
      sTHR = (double)0.1f * Z;
    }
    __syncthreads();
    if (tid < 64) {
      __shared__ double dtmp[2048];
      for (int i = lane; i < nb; i += 64) dtmp[i] = (double)smass[i];
      wave_selectD(dtmp, nb, bitsA[L], lane, &sP, &sPrefix, sTHR);
    }
    __syncthreads();
  }

  const uint32_t tkey = sPrefix;
  const float tstar = scrub(fromkey(tkey));
  if (tid == 0) {
    double ut = (double)__expf(tstar);
    double dd = floor((sTHR - sP) / ut);
    sD = (dd < 0.0) ? 0 : (dd > 2.0e9 ? 2000000000 : (int)dd);
  }
  __syncthreads();

  for (int i = tid; i < nvec; i += FB_TPB) {
    float4 v = *reinterpret_cast<const float4*>(rowp + 4 * i);
    float vv[4] = {v.x, v.y, v.z, v.w};
    float ov[4];
#pragma unroll
    for (int k = 0; k < 4; ++k) {
      uint32_t key = tokey(vv[k]);
      if (key > tkey) {
        ov[k] = scrub(vv[k]);
      } else {
        ov[k] = DROPV;
        if (key == tkey) {
          uint32_t p = atomicAdd(&sTieCnt, 1u);
          if (p < FB_TIE) sTie[p] = (uint32_t)(4 * i + k);
        }
      }
    }
    *reinterpret_cast<float4*>(orow + 4 * i) = make_float4(ov[0], ov[1], ov[2], ov[3]);
  }
  for (int i = tail + tid; i < V; i += FB_TPB) {
    float f = rowp[i];
    uint32_t key = tokey(f);
    float o = DROPV;
    if (key > tkey) o = scrub(f);
    else if (key == tkey) {
      uint32_t p = atomicAdd(&sTieCnt, 1u);
      if (p < FB_TIE) sTie[p] = (uint32_t)i;
    }
    orow[i] = o;
  }
  __syncthreads();

  uint32_t n = sTieCnt;
  if (n > FB_TIE) n = FB_TIE;
  if (n) {
    if (tid == 0) {
      for (uint32_t i2 = 1; i2 < n; ++i2) {
        uint32_t k2 = sTie[i2];
        int j = (int)i2 - 1;
        while (j >= 0 && sTie[j] > k2) { sTie[j + 1] = sTie[j]; --j; }
        sTie[j + 1] = k2;
      }
      if (sD > (int)n - 1) sD = (int)n - 1;
    }
    __syncthreads();
    const int d = sD;
    for (uint32_t j = tid; j < n; j += FB_TPB)
      orow[sTie[j]] = ((int)j >= d) ? tstar : DROPV;
  }
}

extern "C" void kernel_launch(void* const* d_in, const int* in_sizes, int n_in,
                              void* d_out, int out_size, void* d_ws, size_t ws_size,
                              hipStream_t stream) {
  const float* logits = (const float*)d_in[0];
  const int R = in_sizes[1];       // batch = 128 (position_ids unused by ref)
  const int V = in_sizes[0] / R;   // vocab = 128000
  float* out = (float*)d_out;
  (void)out_size; (void)n_in;

  char* ws = (char*)d_ws;
  size_t o = 0;
  auto take = [&](size_t bytes) -> char* {
    char* p = ws + o;
    o = (o + bytes + 7) & ~(size_t)7;
    return p;
  };
  unsigned long long* ghist0 = (unsigned long long*)take(8ull * R * 512);  // 512 KB
  unsigned long long* ghist1 = (unsigned long long*)take(8ull * R * 256);  // 256 KB
  uint32_t* gcnt = (uint32_t*)take(4ull * R);
  const size_t zero_bytes = o;                    // ghist0+ghist1+gcnt start zeroed
  uint2* glist = (uint2*)take(8ull * R * LISTCAP);
  const size_t need = o;                          // ~962 KB at R=128 (< proven 1.0 MB)

  if (ws_size < need || (V & 3) != 0) {
    toppK_fb<<<dim3(R), dim3(FB_TPB), 0, stream>>>(logits, out, V);
    return;
  }

  const int zwords = (int)(zero_bytes / 4);
  zeroK<<<dim3((zwords + TPB - 1) / TPB), dim3(TPB), 0, stream>>>((uint32_t*)ws, zwords);

  dim3 grid(CH, R);
  histZK<<<grid, dim3(TPB), 0, stream>>>(logits, V, ghist0);
  outSelK<<<grid, dim3(TPB), 0, stream>>>(logits, out, V, ghist0, ghist1);
  colSelK<<<grid, dim3(TPB), 0, stream>>>(logits, out, V, ghist0, ghist1, glist, gcnt);
  finSelK<<<dim3(R), dim3(TPB), 0, stream>>>(logits, out, V, ghist0, ghist1, glist, gcnt);
}

// Round 16
// 81.636 us; speedup vs baseline: 1.1972x; 1.1972x over previous
//
#include <hip/hip_runtime.h>
#include <stdint.h>
#include <math.h>

#define TPB 256
#define CH 16           // chunk-blocks per row for heavy passes
#define LISTCAP 160     // per-row final-bin list (lambda~34, P(Pois>160)~e^-100)
#define FIN_TPB 256
#define FB_TPB 1024
#define FB_TIE 1024
#define S_FIX 4096.0f   // fixed-point scale: mass units of 2^-12
// Finite "dropped" sentinel — must be finite IN BF16 TOO (harness diffs via a
// bf16 cast; -FLT_MAX/-inf become bf16 -inf -> (-inf)-(-inf)=NaN -> fail).
#define DROPV (-1.0e30f)

struct SelT { double P; double THR; uint32_t pfx; uint32_t pad; };  // P,THR in fix-units

// order-preserving float->uint32 key (ascending)
__device__ __forceinline__ uint32_t tokey(float f) {
  uint32_t b = __float_as_uint(f);
  return (b & 0x80000000u) ? ~b : (b | 0x80000000u);
}
__device__ __forceinline__ float fromkey(uint32_t k) {
  uint32_t b = (k & 0x80000000u) ? (k ^ 0x80000000u) : ~k;
  return __uint_as_float(b);
}
__device__ __forceinline__ float scrub(float f) {
  uint32_t b = __float_as_uint(f) & 0x7FFFFFFFu;
  if (b >= 0x7F7F0000u) return DROPV;  // inf/NaN or bf16-inf-rounding -> DROPV
  return f;
}
__device__ __forceinline__ unsigned long long tofix(float u) {
  return (unsigned long long)(u * S_FIX);
}

// wave 0: pick lowest bin where running mass crosses THR (bins exact ints in double)
__device__ __forceinline__ void wave_selectD(const double* __restrict__ bins, int nb,
                                             int bits, int lane,
                                             double* sP, uint32_t* sPrefix, double THR) {
  const int per = nb >> 6;
  double lsum = 0.0;
  for (int k = 0; k < per; ++k) lsum += bins[lane * per + k];
  double v = lsum;
#pragma unroll
  for (int off = 1; off < 64; off <<= 1) {
    double o = __shfl_up(v, off, 64);
    if (lane >= off) v += o;
  }
  const double excl = v - lsum;
  const double P = *sP;
  int lbin = -1;
  double lP = 0.0;
  double rr = P + excl;
  for (int k = 0; k < per; ++k) {
    double m = bins[lane * per + k];
    double nr = rr + m;
    if (lbin < 0 && nr > THR) { lbin = lane * per + k; lP = rr; }
    rr = nr;
  }
  unsigned long long got = __ballot(lbin >= 0);
  int bsel;
  double Pn;
  if (got) {
    int src = __ffsll(got) - 1;  // lowest crossing bin
    bsel = __shfl(lbin, src, 64);
    Pn = __shfl(lP, src, 64);
  } else {
    int hb = -1;
    double pb = P;
    rr = P + excl;
    for (int k = 0; k < per; ++k) {
      double m = bins[lane * per + k];
      if (m > 0.0) { hb = lane * per + k; pb = rr; }
      rr += m;
    }
#pragma unroll
    for (int off = 32; off; off >>= 1) {
      int ob = __shfl_xor(hb, off, 64);
      double opb = __shfl_xor(pb, off, 64);
      if (ob > hb) { hb = ob; pb = opb; }
    }
    bsel = hb < 0 ? (nb - 1) : hb;
    Pn = pb;
  }
  if (lane == 0) {
    *sPrefix = (*sPrefix << bits) | (uint32_t)bsel;
    *sP = Pn;
  }
}

__global__ void zeroK(uint32_t* p, int n) {
  int i = blockIdx.x * blockDim.x + threadIdx.x;
  if (i < n) p[i] = 0u;
}

// K1: 9-bit (bits[31:23]) mass histogram, u64 fixed-point, 4-replica LDS.
// Integer LDS atomics (ds_add_u64) are native/pipelined, unlike f32 atomics.
__global__ __launch_bounds__(TPB) void histZK(const float* __restrict__ x, int V,
                                              unsigned long long* __restrict__ ghist) {
  const int row = blockIdx.y, chunk = blockIdx.x, tid = threadIdx.x;
  const float* rowp = x + (size_t)row * (size_t)V;
  __shared__ unsigned long long h[512 * 4];  // 512 bins x 4 replicas = 16 KB
  for (int i = tid; i < 2048; i += TPB) h[i] = 0ull;
  __syncthreads();

  const int epc = (((V + CH - 1) / CH) + 3) & ~3;
  const int start = chunk * epc;
  const int end = min(start + epc, V);
  const int vs = start >> 2, ve = end >> 2;
  const int rep = tid & 3;
  auto acc = [&](float4 v) {
    float vv[4] = {v.x, v.y, v.z, v.w};
#pragma unroll
    for (int k = 0; k < 4; ++k) {
      float u = __expf(vv[k]);  // |logit|<=~17: exp in [4e-8, 3e7], safe f32
      atomicAdd(&h[(((tokey(vv[k]) >> 23) << 2) | rep)], tofix(u));
    }
  };
  for (int i = vs + tid; i < ve; i += 2 * TPB) {  // batch-2 float4 for MLP
    const int i1 = i + TPB;
    const bool g1 = i1 < ve;
    float4 a = *reinterpret_cast<const float4*>(rowp + 4 * i);
    float4 b;
    if (g1) b = *reinterpret_cast<const float4*>(rowp + 4 * i1);
    acc(a);
    if (g1) acc(b);
  }
  for (int i = (ve << 2) + tid; i < end; i += TPB)  // scalar tail
    atomicAdd(&h[(((tokey(rowp[i]) >> 23) << 2) | rep)], tofix(__expf(rowp[i])));
  __syncthreads();
  unsigned long long* gh = ghist + (size_t)row * 512;
  for (int b = tid; b < 512; b += TPB) {
    unsigned long long s = h[4 * b] + h[4 * b + 1] + h[4 * b + 2] + h[4 * b + 3];
    if (s) atomicAdd(&gh[b], s);
  }
}

// K2: Z = sum of hist; level-0 select (9 bits); re-zero hist for level-1 reuse.
__global__ __launch_bounds__(64) void sel0K(unsigned long long* __restrict__ ghist,
                                            SelT* __restrict__ sel) {
  const int row = blockIdx.x, lane = threadIdx.x;
  __shared__ double db[512];
  __shared__ double ssP;
  __shared__ uint32_t ssPfx;
  unsigned long long* gh = ghist + (size_t)row * 512;
  double t = 0.0;
  for (int i = lane; i < 512; i += 64) {
    double d = (double)gh[i];  // exact: Z_units ~ 2^43 < 2^53
    db[i] = d;
    t += d;
  }
#pragma unroll
  for (int off = 32; off; off >>= 1) t += __shfl_xor(t, off, 64);
  const double THR = (double)0.1f * t;  // 0.1f == f32(1.0-0.9), matching ref
  if (lane == 0) { ssP = 0.0; ssPfx = 0u; }
  __syncthreads();
  wave_selectD(db, 512, 9, lane, &ssP, &ssPfx, THR);
  __syncthreads();
  if (lane == 0) {
    SelT s;
    s.P = ssP; s.THR = THR; s.pfx = ssPfx; s.pad = 0u;
    sel[row] = s;
  }
  for (int i = lane; i < 512; i += 64) gh[i] = 0ull;  // reuse for level 1
}

// K3: classify + write output + 9-bit sub-hist (bits[22:14]) of the boundary bin.
__global__ __launch_bounds__(TPB) void outK(const float* __restrict__ x,
                                            float* __restrict__ out, int V,
                                            const SelT* __restrict__ sel,
                                            unsigned long long* __restrict__ ghist) {
  const int row = blockIdx.y, chunk = blockIdx.x, tid = threadIdx.x;
  const float* rowp = x + (size_t)row * (size_t)V;
  float* orow = out + (size_t)row * (size_t)V;
  __shared__ unsigned long long h[512];
  for (int i = tid; i < 512; i += TPB) h[i] = 0ull;
  __syncthreads();
  const uint32_t pfx9 = sel[row].pfx;

  const int epc = (((V + CH - 1) / CH) + 3) & ~3;
  const int start = chunk * epc;
  const int end = min(start + epc, V);
  const int vs = start >> 2, ve = end >> 2;
  auto proc = [&](float4 v, int i) {
    float vv[4] = {v.x, v.y, v.z, v.w};
    float ov[4];
#pragma unroll
    for (int k = 0; k < 4; ++k) {
      uint32_t key = tokey(vv[k]);
      uint32_t top = key >> 23;
      ov[k] = (top > pfx9) ? scrub(vv[k]) : DROPV;  // boundary: placeholder
      if (top == pfx9)
        atomicAdd(&h[(key >> 14) & 511u], tofix(__expf(vv[k])));
    }
    *reinterpret_cast<float4*>(orow + 4 * i) = make_float4(ov[0], ov[1], ov[2], ov[3]);
  };
  for (int i = vs + tid; i < ve; i += 2 * TPB) {
    const int i1 = i + TPB;
    const bool g1 = i1 < ve;
    float4 a = *reinterpret_cast<const float4*>(rowp + 4 * i);
    float4 b;
    if (g1) b = *reinterpret_cast<const float4*>(rowp + 4 * i1);
    proc(a, i);
    if (g1) proc(b, i1);
  }
  for (int i = (ve << 2) + tid; i < end; i += TPB) {
    float f = rowp[i];
    uint32_t key = tokey(f);
    uint32_t top = key >> 23;
    orow[i] = (top > pfx9) ? scrub(f) : DROPV;
    if (top == pfx9) atomicAdd(&h[(key >> 14) & 511u], tofix(__expf(f)));
  }
  __syncthreads();
  unsigned long long* gh = ghist + (size_t)row * 512;
  for (int b = tid; b < 512; b += TPB)
    if (h[b]) atomicAdd(&gh[b], h[b]);
}

// K4: level-1 select (9 more bits) -> 18-bit prefix.
__global__ __launch_bounds__(64) void sel1K(const unsigned long long* __restrict__ ghist,
                                            SelT* __restrict__ sel) {
  const int row = blockIdx.x, lane = threadIdx.x;
  __shared__ double db[512];
  __shared__ double ssP;
  __shared__ uint32_t ssPfx;
  const unsigned long long* gh = ghist + (size_t)row * 512;
  for (int i = lane; i < 512; i += 64) db[i] = (double)gh[i];
  SelT s = sel[row];
  if (lane == 0) { ssP = s.P; ssPfx = s.pfx; }
  __syncthreads();
  wave_selectD(db, 512, 9, lane, &ssP, &ssPfx, s.THR);
  __syncthreads();
  if (lane == 0) {
    s.P = ssP; s.pfx = ssPfx;  // now 18-bit prefix
    sel[row] = s;
  }
}

// K5: restore kept boundary elements above the L1 bin; collect L1-bin elements.
__global__ __launch_bounds__(TPB) void collectK(const float* __restrict__ x,
                                                float* __restrict__ out, int V,
                                                const SelT* __restrict__ sel,
                                                uint2* __restrict__ glist,
                                                uint32_t* __restrict__ gcnt) {
  const int row = blockIdx.y, chunk = blockIdx.x, tid = threadIdx.x;
  const float* rowp = x + (size_t)row * (size_t)V;
  float* orow = out + (size_t)row * (size_t)V;
  const uint32_t pfx18 = sel[row].pfx;
  const uint32_t pfx9 = pfx18 >> 9;
  const uint32_t l1bin = pfx18 & 511u;

  const int epc = (((V + CH - 1) / CH) + 3) & ~3;
  const int start = chunk * epc;
  const int end = min(start + epc, V);
  const int vs = start >> 2, ve = end >> 2;
  auto proc = [&](float f, int idx) {
    uint32_t key = tokey(f);
    if ((key >> 23) == pfx9) {
      uint32_t mid = (key >> 14) & 511u;
      if (mid > l1bin) {
        orow[idx] = scrub(f);  // definitely kept
      } else if (mid == l1bin) {
        uint32_t p = atomicAdd(gcnt + row, 1u);
        if (p < LISTCAP) glist[(size_t)row * LISTCAP + p] = make_uint2(key, (uint32_t)idx);
      }  // mid < l1bin: DROPV placeholder already correct
    }
  };
  for (int i = vs + tid; i < ve; i += 2 * TPB) {
    const int i1 = i + TPB;
    const bool g1 = i1 < ve;
    float4 a = *reinterpret_cast<const float4*>(rowp + 4 * i);
    float4 b;
    if (g1) b = *reinterpret_cast<const float4*>(rowp + 4 * i1);
    proc(a.x, 4 * i); proc(a.y, 4 * i + 1); proc(a.z, 4 * i + 2); proc(a.w, 4 * i + 3);
    if (g1) {
      proc(b.x, 4 * i1); proc(b.y, 4 * i1 + 1); proc(b.z, 4 * i1 + 2); proc(b.w, 4 * i1 + 3);
    }
  }
  for (int i = (ve << 2) + tid; i < end; i += TPB) proc(rowp[i], i);
}

// K6: exact finalize: parallel rank-sort of the L1-bin candidates, then one
// cumulative walk. 256 threads; fallback rescan is parallel+vectorized.
__global__ __launch_bounds__(FIN_TPB) void finK(const float* __restrict__ x,
                                                float* __restrict__ out, int V,
                                                const SelT* __restrict__ sel,
                                                const uint2* __restrict__ glist,
                                                const uint32_t* __restrict__ gcnt) {
  const int row = blockIdx.x, tid = threadIdx.x;
  const float* rowp = x + (size_t)row * (size_t)V;
  float* orow = out + (size_t)row * (size_t)V;
  __shared__ uint2 ls[2048];
  __shared__ uint2 srt[2048];
  __shared__ unsigned char keep[2048];
  __shared__ uint32_t scnt;
  const SelT s = sel[row];
  const uint32_t n0 = gcnt[row];
  if (tid == 0) scnt = 0u;
  __syncthreads();
  uint32_t m;
  if (n0 <= LISTCAP) {
    for (uint32_t i = tid; i < n0; i += FIN_TPB)
      ls[i] = glist[(size_t)row * LISTCAP + i];
    m = n0;
    __syncthreads();
  } else {
    // overflow fallback (statistically never): parallel vectorized rescan
    const uint32_t pfx18 = s.pfx;
    const int nvec = V >> 2;
    for (int i = tid; i < nvec; i += FIN_TPB) {
      float4 v = *reinterpret_cast<const float4*>(rowp + 4 * i);
      float vv[4] = {v.x, v.y, v.z, v.w};
#pragma unroll
      for (int k = 0; k < 4; ++k) {
        uint32_t key = tokey(vv[k]);
        if ((key >> 14) == pfx18) {
          uint32_t p = atomicAdd(&scnt, 1u);
          if (p < 2048u) ls[p] = make_uint2(key, (uint32_t)(4 * i + k));
        }
      }
    }
    for (int i = (nvec << 2) + tid; i < V; i += FIN_TPB) {
      uint32_t key = tokey(rowp[i]);
      if ((key >> 14) == pfx18) {
        uint32_t p = atomicAdd(&scnt, 1u);
        if (p < 2048u) ls[p] = make_uint2(key, (uint32_t)i);
      }
    }
    __syncthreads();
    m = min(scnt, 2048u);
  }

  // parallel rank placement: rank by (key, idx) — unique since idx unique
  for (uint32_t j = tid; j < m; j += FIN_TPB) {
    uint2 kv = ls[j];
    uint32_t r = 0;
    for (uint32_t i = 0; i < m; ++i) {
      uint2 o = ls[i];
      if (o.x < kv.x || (o.x == kv.x && o.y < kv.y)) ++r;
    }
    srt[r] = kv;
  }
  __syncthreads();
  if (tid == 0) {
    // cumulative walk in ascending stable order == ref's sorted cumsum
    double cum = s.P;  // fix-units
    for (uint32_t j = 0; j < m; ++j) {
      cum += (double)__expf(fromkey(srt[j].x)) * (double)S_FIX;
      keep[j] = (cum > s.THR) ? 1 : 0;
    }
  }
  __syncthreads();
  for (uint32_t j = tid; j < m; j += FIN_TPB)
    orow[srt[j].y] = keep[j] ? scrub(fromkey(srt[j].x)) : DROPV;
}

// ---------------- fallback: proven single-kernel path (ws too small) ----------------
__global__ __launch_bounds__(FB_TPB) void toppK_fb(const float* __restrict__ x,
                                                   float* __restrict__ out, int V) {
  const int row = blockIdx.x;
  const int tid = threadIdx.x;
  const int lane = tid & 63;
  const float* rowp = x + (size_t)row * (size_t)V;
  float* orow = out + (size_t)row * (size_t)V;
  const int nvec = V >> 2;
  const int tail = nvec << 2;

  __shared__ float smass[2048];
  __shared__ double zw[FB_TPB / 64];
  __shared__ double sTHR, sP;
  __shared__ uint32_t sPrefix;
  __shared__ uint32_t sTie[FB_TIE];
  __shared__ uint32_t sTieCnt;
  __shared__ int sD;

  if (tid == 0) { sTieCnt = 0u; sPrefix = 0u; sP = 0.0; sTHR = 0.0; sD = 0; }
  const int shifts[3] = {21, 10, 0};
  const int bitsA[3] = {11, 11, 10};

  for (int L = 0; L < 3; ++L) {
    const int nb = 1 << bitsA[L];
    for (int i = tid; i < nb; i += FB_TPB) smass[i] = 0.f;
    __syncthreads();
    const uint32_t pfx = sPrefix;
    float zloc = 0.f;
    for (int i = tid; i < nvec; i += FB_TPB) {
      float4 v = *reinterpret_cast<const float4*>(rowp + 4 * i);
      float vv[4] = {v.x, v.y, v.z, v.w};
#pragma unroll
      for (int k = 0; k < 4; ++k) {
        uint32_t key = tokey(vv[k]);
        if (L == 0) {
          float u = __expf(vv[k]);
          zloc += u;
          atomicAdd(&smass[key >> 21], u);
        } else if ((key >> (shifts[L] + bitsA[L])) == pfx) {
          atomicAdd(&smass[(key >> shifts[L]) & (uint32_t)(nb - 1)], __expf(vv[k]));
        }
      }
    }
    for (int i = tail + tid; i < V; i += FB_TPB) {
      float f = rowp[i];
      uint32_t key = tokey(f);
      if (L == 0) {
        float u = __expf(f);
        zloc += u;
        atomicAdd(&smass[key >> 21], u);
      } else if ((key >> (shifts[L] + bitsA[L])) == pfx) {
        atomicAdd(&smass[(key >> shifts[L]) & (uint32_t)(nb - 1)], __expf(f));
      }
    }
    if (L == 0) {
      double z = (double)zloc;
#pragma unroll
      for (int off = 32; off; off >>= 1) z += __shfl_down(z, off, 64);
      if (lane == 0) zw[tid >> 6] = z;
    }
    __syncthreads();
    if (L == 0 && tid == 0) {
      double Z = 0.0;
      for (int w = 0; w < FB_TPB / 64; ++w) Z += zw[w];
      sTHR = (double)0.1f * Z;
    }
    __syncthreads();
    if (tid < 64) {
      __shared__ double dtmp[2048];
      for (int i = lane; i < nb; i += 64) dtmp[i] = (double)smass[i];
      wave_selectD(dtmp, nb, bitsA[L], lane, &sP, &sPrefix, sTHR);
    }
    __syncthreads();
  }

  const uint32_t tkey = sPrefix;
  const float tstar = scrub(fromkey(tkey));
  if (tid == 0) {
    double ut = (double)__expf(tstar);
    double dd = floor((sTHR - sP) / ut);
    sD = (dd < 0.0) ? 0 : (dd > 2.0e9 ? 2000000000 : (int)dd);
  }
  __syncthreads();

  for (int i = tid; i < nvec; i += FB_TPB) {
    float4 v = *reinterpret_cast<const float4*>(rowp + 4 * i);
    float vv[4] = {v.x, v.y, v.z, v.w};
    float ov[4];
#pragma unroll
    for (int k = 0; k < 4; ++k) {
      uint32_t key = tokey(vv[k]);
      if (key > tkey) {
        ov[k] = scrub(vv[k]);
      } else {
        ov[k] = DROPV;
        if (key == tkey) {
          uint32_t p = atomicAdd(&sTieCnt, 1u);
          if (p < FB_TIE) sTie[p] = (uint32_t)(4 * i + k);
        }
      }
    }
    *reinterpret_cast<float4*>(orow + 4 * i) = make_float4(ov[0], ov[1], ov[2], ov[3]);
  }
  for (int i = tail + tid; i < V; i += FB_TPB) {
    float f = rowp[i];
    uint32_t key = tokey(f);
    float o = DROPV;
    if (key > tkey) o = scrub(f);
    else if (key == tkey) {
      uint32_t p = atomicAdd(&sTieCnt, 1u);
      if (p < FB_TIE) sTie[p] = (uint32_t)i;
    }
    orow[i] = o;
  }
  __syncthreads();

  uint32_t n = sTieCnt;
  if (n > FB_TIE) n = FB_TIE;
  if (n) {
    if (tid == 0) {
      for (uint32_t i2 = 1; i2 < n; ++i2) {
        uint32_t k2 = sTie[i2];
        int j = (int)i2 - 1;
        while (j >= 0 && sTie[j] > k2) { sTie[j + 1] = sTie[j]; --j; }
        sTie[j + 1] = k2;
      }
      if (sD > (int)n - 1) sD = (int)n - 1;
    }
    __syncthreads();
    const int d = sD;
    for (uint32_t j = tid; j < n; j += FB_TPB)
      orow[sTie[j]] = ((int)j >= d) ? tstar : DROPV;
  }
}

extern "C" void kernel_launch(void* const* d_in, const int* in_sizes, int n_in,
                              void* d_out, int out_size, void* d_ws, size_t ws_size,
                              hipStream_t stream) {
  const float* logits = (const float*)d_in[0];
  const int R = in_sizes[1];       // batch = 128 (position_ids unused by ref)
  const int V = in_sizes[0] / R;   // vocab = 128000
  float* out = (float*)d_out;
  (void)out_size; (void)n_in;

  char* ws = (char*)d_ws;
  size_t o = 0;
  auto take = [&](size_t bytes) -> char* {
    char* p = ws + o;
    o = (o + bytes + 7) & ~(size_t)7;
    return p;
  };
  unsigned long long* ghist = (unsigned long long*)take(8ull * R * 512);  // 512 KB, reused L0->L1
  uint32_t* gcnt = (uint32_t*)take(4ull * R);
  const size_t zero_bytes = o;                    // ghist + gcnt must start zeroed
  SelT* sel = (SelT*)take(sizeof(SelT) * R);      // written before read
  uint2* glist = (uint2*)take(8ull * R * LISTCAP);
  const size_t need = o;                          // ~680 KB at R=128 (< proven 962 KB)

  if (ws_size < need || (V & 3) != 0) {
    toppK_fb<<<dim3(R), dim3(FB_TPB), 0, stream>>>(logits, out, V);
    return;
  }

  const int zwords = (int)(zero_bytes / 4);
  zeroK<<<dim3((zwords + TPB - 1) / TPB), dim3(TPB), 0, stream>>>((uint32_t*)ws, zwords);

  dim3 grid(CH, R);
  histZK<<<grid, dim3(TPB), 0, stream>>>(logits, V, ghist);
  sel0K<<<dim3(R), dim3(64), 0, stream>>>(ghist, sel);
  outK<<<grid, dim3(TPB), 0, stream>>>(logits, out, V, sel, ghist);
  sel1K<<<dim3(R), dim3(64), 0, stream>>>(ghist, sel);
  collectK<<<grid, dim3(TPB), 0, stream>>>(logits, out, V, sel, glist, gcnt);
  finK<<<dim3(R), dim3(FIN_TPB), 0, stream>>>(logits, out, V, sel, glist, gcnt);
}